// Round 1
// baseline (254.619 us; speedup 1.0000x reference)
//
#include <hip/hip_runtime.h>

#define BATCH 32
#define NN 116
#define EE 1346
#define HH 64
#define CE 85      // e-chunk per split (16*85 = 1360 >= 1346)
#define SPLITS 16

// ---------------- Kernel B: mult1[b,n,m] = sum_e T[b,n,e]*de[b,e]*T[b,m,e] ----------------
// de computed inline from He . p_v. Split-K over e; partials atomically accumulated.
__global__ __launch_bounds__(256) void de_mult1_kernel(
    const float* __restrict__ T, const float* __restrict__ He,
    const float* __restrict__ pv, float* __restrict__ mult1)
{
    const int b  = blockIdx.y;
    const int s  = blockIdx.x;
    const int e0 = s * CE;
    const int count = min(CE, EE - e0);
    const int tid = threadIdx.x;

    __shared__ float Tl[CE * 128];   // swizzled [e][n], n padded to 128
    __shared__ float del[CE];

    const float p0 = pv[0], p1 = pv[1], p2 = pv[2], p3 = pv[3], p4 = pv[4];

    // de for this e-chunk
    for (int i = tid; i < CE; i += 256) {
        float v = 0.f;
        if (i < count) {
            const float* he = He + (size_t)(b * EE + e0 + i) * 5;
            v = he[0]*p0 + he[1]*p1 + he[2]*p2 + he[3]*p3 + he[4]*p4;
        }
        del[i] = v;
    }
    // Load T chunk (coalesced along e), XOR-swizzled store so both the strided
    // writes and the float4 reads are bank-conflict-free.
    for (int idx = tid; idx < 128 * CE; idx += 256) {
        const int n = idx / CE;
        const int e = idx - n * CE;
        float v = 0.f;
        if (n < NN && e < count)
            v = T[(size_t)(b * NN + n) * EE + e0 + e];
        Tl[e * 128 + (n ^ (4 * (e & 31)))] = v;
    }
    __syncthreads();

    const int tx = tid & 15, ty = tid >> 4;
    const int na = 4 * tx, nb = 64 + 4 * tx;
    const int ma = 4 * ty, mb = 64 + 4 * ty;

    float acc[8][8];
    #pragma unroll
    for (int i = 0; i < 8; ++i)
        #pragma unroll
        for (int j = 0; j < 8; ++j) acc[i][j] = 0.f;

    for (int e = 0; e < count; ++e) {
        const int base = e * 128;
        const int swz  = 4 * (e & 31);
        const float d  = del[e];
        float4 a0 = *(const float4*)&Tl[base + (na ^ swz)];
        float4 a1 = *(const float4*)&Tl[base + (nb ^ swz)];
        float4 b0 = *(const float4*)&Tl[base + (ma ^ swz)];
        float4 b1 = *(const float4*)&Tl[base + (mb ^ swz)];
        a0.x *= d; a0.y *= d; a0.z *= d; a0.w *= d;
        a1.x *= d; a1.y *= d; a1.z *= d; a1.w *= d;
        const float av[8] = {a0.x,a0.y,a0.z,a0.w,a1.x,a1.y,a1.z,a1.w};
        const float bv[8] = {b0.x,b0.y,b0.z,b0.w,b1.x,b1.y,b1.z,b1.w};
        #pragma unroll
        for (int i = 0; i < 8; ++i)
            #pragma unroll
            for (int j = 0; j < 8; ++j)
                acc[i][j] = fmaf(av[i], bv[j], acc[i][j]);
    }

    #pragma unroll
    for (int i = 0; i < 8; ++i) {
        const int n = (i < 4) ? (na + i) : (nb + i - 4);
        if (n >= NN) continue;
        #pragma unroll
        for (int j = 0; j < 8; ++j) {
            const int m = (j < 4) ? (ma + j) : (mb + j - 4);
            if (m >= NN) continue;
            atomicAdd(&mult1[((size_t)b * NN + n) * NN + m], acc[i][j]);
        }
    }
}

// ---------------- Kernel H: HvW[b,n,h] = sum_k Hv[b,n,k] * W_v[k,h] ----------------
// wave = one (b,n) row x 64 h lanes: Hv scalar broadcast, W_v coalesced, L1/L2 resident.
__global__ __launch_bounds__(256) void hvw_kernel(
    const float* __restrict__ Hv, const float* __restrict__ Wv,
    float* __restrict__ HvW)
{
    const int lin = blockIdx.x * 4 + (threadIdx.x >> 6);  // b*NN + n
    const int h   = threadIdx.x & 63;
    if (lin >= BATCH * NN) return;
    const float* hv = Hv + (size_t)lin * NN;
    float acc = 0.f;
    #pragma unroll 4
    for (int k = 0; k < NN; ++k)
        acc = fmaf(hv[k], Wv[k * HH + h], acc);
    HvW[(size_t)lin * HH + h] = acc;
}

// ------- Kernel C2: Hv' = LReLU(adjA @ HvW + b_v); pooled[b,h] += Hv'[b,n,h] -------
__global__ __launch_bounds__(256) void node_out_kernel(
    const float* __restrict__ mult1, const float* __restrict__ Av,
    const float* __restrict__ HvW, const float* __restrict__ bv,
    float* __restrict__ pooled)
{
    const int lin = blockIdx.x * 4 + (threadIdx.x >> 6);  // b*NN + n
    const int h   = threadIdx.x & 63;
    if (lin >= BATCH * NN) return;
    const int b = lin / NN;
    const int n = lin - b * NN;
    const float* m1 = mult1 + (size_t)lin * NN;
    const float* av = Av    + (size_t)lin * NN;
    const float* hw = HvW   + (size_t)b * NN * HH + h;
    float acc = 0.f;
    for (int m = 0; m < NN; ++m) {
        const float a = av[m] * ((m == n) ? 1.0f : m1[m]);
        acc = fmaf(a, hw[(size_t)m * HH], acc);
    }
    float x = acc + bv[h];
    x = (x >= 0.f) ? x : 0.01f * x;   // LeakyReLU(0.01)
    atomicAdd(&pooled[b * HH + h], x);
}

// ---------------- Kernel D: out[b,o] = (pooled[b]/N) @ W_fc + b_fc ----------------
__global__ __launch_bounds__(128) void head_kernel(
    const float* __restrict__ pooled, const float* __restrict__ Wfc,
    const float* __restrict__ bfc, float* __restrict__ out)
{
    const int t = threadIdx.x;
    if (t >= BATCH * 4) return;
    const int b = t >> 2, o = t & 3;
    float acc = 0.f;
    #pragma unroll 8
    for (int hh = 0; hh < HH; ++hh)
        acc = fmaf(pooled[b * HH + hh], Wfc[hh * 4 + o], acc);
    out[t] = acc * (1.0f / NN) + bfc[o];
}

extern "C" void kernel_launch(void* const* d_in, const int* in_sizes, int n_in,
                              void* d_out, int out_size, void* d_ws, size_t ws_size,
                              hipStream_t stream) {
    const float* H_v   = (const float*)d_in[0];
    const float* H_e   = (const float*)d_in[1];
    const float* adj_v = (const float*)d_in[2];
    // d_in[3] = adj_e  : dead for the returned output
    const float* T     = (const float*)d_in[4];
    const float* W_v   = (const float*)d_in[5];
    const float* p_v   = (const float*)d_in[6];
    const float* b_v   = (const float*)d_in[7];
    // d_in[8,9,10] = W_e, p_e, b_e : dead
    const float* W_fc  = (const float*)d_in[11];
    const float* b_fc  = (const float*)d_in[12];
    float* out = (float*)d_out;

    float* mult1  = (float*)d_ws;                    // [32][116][116]
    float* HvW    = mult1 + (size_t)BATCH * NN * NN; // [32][116][64]
    float* pooled = HvW   + (size_t)BATCH * NN * HH; // [32][64]
    const size_t zbytes = ((size_t)BATCH * NN * NN +
                           (size_t)BATCH * NN * HH +
                           (size_t)BATCH * HH) * sizeof(float);

    hipMemsetAsync(d_ws, 0, zbytes, stream);

    de_mult1_kernel<<<dim3(SPLITS, BATCH), 256, 0, stream>>>(T, H_e, p_v, mult1);
    hvw_kernel    <<<dim3((BATCH * NN) / 4), 256, 0, stream>>>(H_v, W_v, HvW);
    node_out_kernel<<<dim3((BATCH * NN) / 4), 256, 0, stream>>>(mult1, adj_v, HvW, b_v, pooled);
    head_kernel   <<<1, 128, 0, stream>>>(pooled, W_fc, b_fc, out);
}

// Round 2
// 119.891 us; speedup vs baseline: 2.1237x; 2.1237x over previous
//
#include <hip/hip_runtime.h>

#define BATCH 32
#define NN 116
#define EE 1346
#define HH 64
#define SPLITS 8
#define ECH 170     // e per split block: 8*170 = 1360 >= 1346
#define KE 32       // e per LDS chunk
#define ITEMS 15    // ceil(116*32 / 256)

// ---- Stage 1: part[s][b][n][m] = sum_{e in chunk s} T[b,n,e]*de[b,e]*T[b,m,e] ----
// 4 waves/block, each wave computes one 64x64 tile (2x2 tiles cover 116x116).
__global__ __launch_bounds__(256) void mult1_part_kernel(
    const float* __restrict__ T, const float* __restrict__ He,
    const float* __restrict__ pv, float* __restrict__ part)
{
    const int b   = blockIdx.y;
    const int s   = blockIdx.x;
    const int e0  = s * ECH;
    const int cnt = min(ECH, EE - e0);
    const int tid = threadIdx.x;
    const int wv  = tid >> 6;
    const int lane = tid & 63;
    const int tx = lane & 7, ty = lane >> 3;
    const int wi = (wv >> 1) * 64;   // tile row origin
    const int wj = (wv & 1) * 64;    // tile col origin

    __shared__ float Tl[KE][128];
    __shared__ float del[ECH];

    // de = He . p_v for this block's e-range
    {
        const float p0 = pv[0], p1 = pv[1], p2 = pv[2], p3 = pv[3], p4 = pv[4];
        for (int i = tid; i < ECH; i += 256) {
            float v = 0.f;
            if (i < cnt) {
                const float* he = He + (size_t)(b * EE + e0 + i) * 5;
                v = he[0]*p0 + he[1]*p1 + he[2]*p2 + he[3]*p3 + he[4]*p4;
            }
            del[i] = v;
        }
    }

    float acc[8][8];
    #pragma unroll
    for (int i = 0; i < 8; ++i)
        #pragma unroll
        for (int j = 0; j < 8; ++j) acc[i][j] = 0.f;

    const int nchunk = (cnt + KE - 1) / KE;

    // prefetch chunk 0 into registers
    float pref[ITEMS];
    #pragma unroll
    for (int it = 0; it < ITEMS; ++it) {
        const int idx = tid + it * 256;
        float v = 0.f;
        if (idx < NN * KE) {
            const int n = idx >> 5, e = idx & 31;
            if (e < cnt) v = T[(size_t)(b * NN + n) * EE + e0 + e];
        }
        pref[it] = v;
    }
    __syncthreads();   // del ready

    for (int c = 0; c < nchunk; ++c) {
        // write prefetched chunk c to LDS (XOR-swizzled)
        #pragma unroll
        for (int it = 0; it < ITEMS; ++it) {
            const int idx = tid + it * 256;
            if (idx < NN * KE) {
                const int n = idx >> 5, e = idx & 31;
                Tl[e][n ^ (e << 2)] = pref[it];
            }
        }
        __syncthreads();

        // prefetch chunk c+1
        if (c + 1 < nchunk) {
            const int ebase = (c + 1) * KE;
            #pragma unroll
            for (int it = 0; it < ITEMS; ++it) {
                const int idx = tid + it * 256;
                float v = 0.f;
                if (idx < NN * KE) {
                    const int n = idx >> 5, e = ebase + (idx & 31);
                    if (e < cnt) v = T[(size_t)(b * NN + n) * EE + e0 + e];
                }
                pref[it] = v;
            }
        }

        // compute chunk c
        const int elim = min(KE, cnt - c * KE);
        const float* dl = &del[c * KE];
        #pragma unroll 8
        for (int e = 0; e < elim; ++e) {
            const float d = dl[e];
            const int swz = e << 2;
            float4 a0 = *(const float4*)&Tl[e][(wi +      tx * 4) ^ swz];
            float4 a1 = *(const float4*)&Tl[e][(wi + 32 + tx * 4) ^ swz];
            float4 b0 = *(const float4*)&Tl[e][(wj +      ty * 4) ^ swz];
            float4 b1 = *(const float4*)&Tl[e][(wj + 32 + ty * 4) ^ swz];
            a0.x *= d; a0.y *= d; a0.z *= d; a0.w *= d;
            a1.x *= d; a1.y *= d; a1.z *= d; a1.w *= d;
            const float av[8] = {a0.x,a0.y,a0.z,a0.w,a1.x,a1.y,a1.z,a1.w};
            const float bv[8] = {b0.x,b0.y,b0.z,b0.w,b1.x,b1.y,b1.z,b1.w};
            #pragma unroll
            for (int i = 0; i < 8; ++i)
                #pragma unroll
                for (int j = 0; j < 8; ++j)
                    acc[i][j] = fmaf(av[i], bv[j], acc[i][j]);
        }
        __syncthreads();
    }

    // epilogue: plain stores to this split's private partial buffer
    float* pb = part + (((size_t)s * BATCH + b) * NN) * NN;
    #pragma unroll
    for (int i = 0; i < 8; ++i) {
        const int n = wi + ((i < 4) ? (tx * 4 + i) : (32 + tx * 4 + i - 4));
        if (n >= NN) continue;
        float* row = pb + (size_t)n * NN;
        const int m0 = wj + ty * 4;
        float4 v0 = {acc[i][0], acc[i][1], acc[i][2], acc[i][3]};
        *(float4*)&row[m0] = v0;   // m0+3 <= 95 < 116 always
        const int m1 = wj + 32 + ty * 4;
        if (m1 + 3 < NN) {
            float4 v1 = {acc[i][4], acc[i][5], acc[i][6], acc[i][7]};
            *(float4*)&row[m1] = v1;
        } else {
            #pragma unroll
            for (int j = 4; j < 8; ++j)
                if (m1 + j - 4 < NN) row[m1 + j - 4] = acc[i][j];
        }
    }
}

// ---- HvW[b,n,h] = sum_k Hv[b,n,k] * W_v[k,h] : wave = one row x 64 h lanes ----
__global__ __launch_bounds__(256) void hvw_kernel(
    const float* __restrict__ Hv, const float* __restrict__ Wv,
    float* __restrict__ HvW)
{
    const int lin = blockIdx.x * 4 + (threadIdx.x >> 6);
    const int h   = threadIdx.x & 63;
    if (lin >= BATCH * NN) return;
    const float* hv = Hv + (size_t)lin * NN;
    float acc = 0.f;
    #pragma unroll 4
    for (int k = 0; k < NN; ++k)
        acc = fmaf(hv[k], Wv[k * HH + h], acc);
    HvW[(size_t)lin * HH + h] = acc;
}

// ---- Hv' = LReLU((Av .* fix_diag(sum_s part)) @ HvW + b_v), written to Hvp ----
__global__ __launch_bounds__(256) void node_out_kernel(
    const float* __restrict__ part, const float* __restrict__ Av,
    const float* __restrict__ HvW, const float* __restrict__ bv,
    float* __restrict__ Hvp)
{
    const int lin = blockIdx.x * 4 + (threadIdx.x >> 6);
    const int h   = threadIdx.x & 63;
    if (lin >= BATCH * NN) return;
    const int b = lin / NN;
    const int n = lin - b * NN;
    const float* av = Av + (size_t)lin * NN;
    const float* hw = HvW + (size_t)b * NN * HH + h;
    const float* pr = part + ((size_t)b * NN + n) * NN;
    const size_t sstr = (size_t)BATCH * NN * NN;
    float acc = 0.f;
    for (int m = 0; m < NN; ++m) {
        float msum = 0.f;
        #pragma unroll
        for (int s = 0; s < SPLITS; ++s) msum += pr[s * sstr + m];
        const float a = av[m] * ((m == n) ? 1.0f : msum);
        acc = fmaf(a, hw[(size_t)m * HH], acc);
    }
    float x = acc + bv[h];
    Hvp[(size_t)lin * HH + h] = (x >= 0.f) ? x : 0.01f * x;
}

// ---- head: pooled = mean_n Hv'; out = pooled @ W_fc + b_fc ----
__global__ __launch_bounds__(64) void head_kernel(
    const float* __restrict__ Hvp, const float* __restrict__ Wfc,
    const float* __restrict__ bfc, float* __restrict__ out)
{
    const int b = blockIdx.x;
    const int h = threadIdx.x;
    float s = 0.f;
    for (int n = 0; n < NN; ++n)
        s += Hvp[((size_t)b * NN + n) * HH + h];
    __shared__ float pool[HH];
    pool[h] = s * (1.0f / NN);
    __syncthreads();
    if (h < 4) {
        float acc = bfc[h];
        #pragma unroll 8
        for (int k = 0; k < HH; ++k)
            acc = fmaf(pool[k], Wfc[k * 4 + h], acc);
        out[b * 4 + h] = acc;
    }
}

extern "C" void kernel_launch(void* const* d_in, const int* in_sizes, int n_in,
                              void* d_out, int out_size, void* d_ws, size_t ws_size,
                              hipStream_t stream) {
    const float* H_v   = (const float*)d_in[0];
    const float* H_e   = (const float*)d_in[1];
    const float* adj_v = (const float*)d_in[2];
    // d_in[3] = adj_e : dead for the returned output
    const float* T     = (const float*)d_in[4];
    const float* W_v   = (const float*)d_in[5];
    const float* p_v   = (const float*)d_in[6];
    const float* b_v   = (const float*)d_in[7];
    // d_in[8,9,10] = W_e, p_e, b_e : dead
    const float* W_fc  = (const float*)d_in[11];
    const float* b_fc  = (const float*)d_in[12];
    float* out = (float*)d_out;

    float* part = (float*)d_ws;                                  // [8][32][116][116]
    float* HvW  = part + (size_t)SPLITS * BATCH * NN * NN;       // [32][116][64]
    float* Hvp  = HvW  + (size_t)BATCH * NN * HH;                // [32][116][64]

    mult1_part_kernel<<<dim3(SPLITS, BATCH), 256, 0, stream>>>(T, H_e, p_v, part);
    hvw_kernel       <<<dim3((BATCH * NN + 3) / 4), 256, 0, stream>>>(H_v, W_v, HvW);
    node_out_kernel  <<<dim3((BATCH * NN + 3) / 4), 256, 0, stream>>>(part, adj_v, HvW, b_v, Hvp);
    head_kernel      <<<BATCH, 64, 0, stream>>>(Hvp, W_fc, b_fc, out);
}

// Round 3
// 53.932 us; speedup vs baseline: 4.7211x; 2.2230x over previous
//
#include <hip/hip_runtime.h>

#define BATCH 32
#define NN 116
#define EE 1346
#define HH 64
#define SPLITS 8
#define ECH 170        // K per split: 8*170 = 1360 >= 1346
#define PROW 128       // partial-buffer row stride

typedef __attribute__((ext_vector_type(8))) short bf16x8;
typedef __attribute__((ext_vector_type(4))) float f32x4;

__device__ __forceinline__ unsigned int pack_bf16(float a, float b) {
    union { float f; unsigned int u; } ua, ub;
    ua.f = a; ub.f = b;
    unsigned int lo = (ua.u + 0x7FFFu + ((ua.u >> 16) & 1u)) >> 16;
    unsigned int hi = (ub.u + 0x7FFFu + ((ub.u >> 16) & 1u)) >> 16;
    return lo | (hi << 16);
}

// ---- Stage 1 (MFMA): part[s][b][n][m] = sum_{e in split s} T[b,n,e]*de[b,e]*T[b,m,e] ----
__global__ __launch_bounds__(256) void mult1_mfma_kernel(
    const float* __restrict__ T, const float* __restrict__ He,
    const float* __restrict__ pv, float* __restrict__ part)
{
    const int s = blockIdx.x, b = blockIdx.y;
    const int e0 = s * ECH;
    const int cnt = min(ECH, EE - e0);          // 170 (s<7) or 156 (s==7)
    const int nsteps = (cnt + 31) >> 5;
    const int tid = threadIdx.x;

    __shared__ float del[192];                   // de for this split, zero-padded
    __shared__ unsigned int Tt[128 * 16];        // [row][32k] bf16, XOR-swizzled
    __shared__ unsigned int dTt[128 * 16];

    // de = He . p_v
    {
        const float p0 = pv[0], p1 = pv[1], p2 = pv[2], p3 = pv[3], p4 = pv[4];
        for (int i = tid; i < 192; i += 256) {
            float v = 0.f;
            if (i < cnt) {
                const float* he = He + (size_t)(b * EE + e0 + i) * 5;
                v = he[0]*p0 + he[1]*p1 + he[2]*p2 + he[3]*p3 + he[4]*p4;
            }
            del[i] = v;
        }
    }

    const int n  = tid >> 1;        // staging row
    const int hf = tid & 1;         // k half (16 floats)
    const float* src = T + ((size_t)b * NN + n) * EE + e0;

    float2 pf[8];
    auto prefetch = [&](int c) {
        const int kb = c * 32 + hf * 16;
        #pragma unroll
        for (int q = 0; q < 8; ++q) {
            float2 v = {0.f, 0.f};
            const int k = kb + q * 2;
            if (n < NN) {
                if (k + 1 < cnt) v = *(const float2*)&src[k];   // 8B-aligned always
                else {
                    if (k < cnt) v.x = src[k];
                }
            }
            pf[q] = v;
        }
    };

    const int w  = tid >> 6, lane = tid & 63;
    const int RO = (w >> 1) * 64, CO = (w & 1) * 64;
    const int rl = lane & 15, g = lane >> 4;

    f32x4 acc[4][4] = {};

    prefetch(0);
    __syncthreads();    // del visible

    for (int c = 0; c < nsteps; ++c) {
        // write staged chunk to LDS (bf16, swizzled); dT = T * de
        {
            const int kb = c * 32 + hf * 16;
            #pragma unroll
            for (int q2 = 0; q2 < 2; ++q2) {
                uint4 tq, dq;
                unsigned int* tp = &tq.x;
                unsigned int* dp = &dq.x;
                #pragma unroll
                for (int j = 0; j < 4; ++j) {
                    const float2 v = pf[q2 * 4 + j];
                    const float2 d = *(const float2*)&del[kb + q2 * 8 + 2 * j];
                    tp[j] = pack_bf16(v.x, v.y);
                    dp[j] = pack_bf16(v.x * d.x, v.y * d.y);
                }
                const int byteoff = ((n * 64) + (hf * 32) + (q2 * 16)) ^ ((n & 7) << 4);
                *(uint4*)((char*)Tt  + byteoff) = tq;
                *(uint4*)((char*)dTt + byteoff) = dq;
            }
        }
        __syncthreads();    // tiles visible

        if (c + 1 < nsteps) prefetch(c + 1);   // hide next chunk's HBM latency

        // frags + 16 MFMA per wave (64x64 quadrant)
        bf16x8 af[4], bf[4];
        #pragma unroll
        for (int t = 0; t < 4; ++t) {
            const int ra = RO + t * 16 + rl;
            const int rb = CO + t * 16 + rl;
            af[t] = *(const bf16x8*)((const char*)dTt + (((ra * 64) + g * 16) ^ ((ra & 7) << 4)));
            bf[t] = *(const bf16x8*)((const char*)Tt  + (((rb * 64) + g * 16) ^ ((rb & 7) << 4)));
        }
        #pragma unroll
        for (int tn = 0; tn < 4; ++tn)
            #pragma unroll
            for (int tm = 0; tm < 4; ++tm)
                acc[tn][tm] = __builtin_amdgcn_mfma_f32_16x16x32_bf16(
                    af[tn], bf[tm], acc[tn][tm], 0, 0, 0);
        __syncthreads();    // before next overwrite
    }

    // epilogue: f32 partial store (mult1 is symmetric -> layout transposes harmless)
    float* pb = part + ((size_t)(s * BATCH + b) * NN) * PROW;
    #pragma unroll
    for (int tn = 0; tn < 4; ++tn) {
        #pragma unroll
        for (int r = 0; r < 4; ++r) {
            const int grow = RO + tn * 16 + g * 4 + r;
            if (grow >= NN) continue;
            float* rowp = pb + (size_t)grow * PROW + CO;
            #pragma unroll
            for (int tm = 0; tm < 4; ++tm)
                rowp[tm * 16 + rl] = acc[tn][tm][r];
        }
    }
}

// ---- HvW[b,n,h] = sum_k Hv[b,n,k] * W_v[k,h] : wave = one row x 64 h lanes ----
__global__ __launch_bounds__(256) void hvw_kernel(
    const float* __restrict__ Hv, const float* __restrict__ Wv,
    float* __restrict__ HvW)
{
    const int lin = blockIdx.x * 4 + (threadIdx.x >> 6);
    const int h   = threadIdx.x & 63;
    if (lin >= BATCH * NN) return;
    const float* hv = Hv + (size_t)lin * NN;
    float acc = 0.f;
    #pragma unroll 4
    for (int k = 0; k < NN; ++k)
        acc = fmaf(hv[k], Wv[k * HH + h], acc);
    HvW[(size_t)lin * HH + h] = acc;
}

// ---- Hv' = LReLU((Av .* fix_diag(sum_s part)) @ HvW + b_v) ----
// Block = 4 rows: cooperative LDS build of adjA rows, then wave-GEMV.
__global__ __launch_bounds__(256) void node_out_kernel(
    const float* __restrict__ part, const float* __restrict__ Av,
    const float* __restrict__ HvW, const float* __restrict__ bv,
    float* __restrict__ Hvp)
{
    const int blk = blockIdx.x;            // 928 blocks; 116/4=29 -> never crosses b
    const int tid = threadIdx.x;
    const int lin0 = blk * 4;
    const int b  = lin0 / NN;
    const int n0 = lin0 - b * NN;

    __shared__ float adjs[4][128];
    const size_t sstr = (size_t)BATCH * NN * PROW;
    #pragma unroll
    for (int it = 0; it < 2; ++it) {
        const int idx = tid + it * 256;
        const int r = idx >> 7, m = idx & 127;
        float v = 0.f;
        if (m < NN) {
            const size_t rowoff = ((size_t)b * NN + n0 + r) * PROW + m;
            float msum = 0.f;
            #pragma unroll
            for (int s = 0; s < SPLITS; ++s) msum += part[s * sstr + rowoff];
            const float a = Av[(size_t)(lin0 + r) * NN + m];
            v = a * ((m == n0 + r) ? 1.0f : msum);
        }
        adjs[r][m] = v;
    }
    __syncthreads();

    const int w = tid >> 6, h = tid & 63;
    const float* hw = HvW + (size_t)b * NN * HH + h;
    float acc = 0.f;
    #pragma unroll 4
    for (int m = 0; m < NN; ++m)
        acc = fmaf(adjs[w][m], hw[(size_t)m * HH], acc);
    float x = acc + bv[h];
    Hvp[(size_t)(lin0 + w) * HH + h] = (x >= 0.f) ? x : 0.01f * x;
}

// ---- head: pooled = mean_n Hv'; out = pooled @ W_fc + b_fc ----
__global__ __launch_bounds__(64) void head_kernel(
    const float* __restrict__ Hvp, const float* __restrict__ Wfc,
    const float* __restrict__ bfc, float* __restrict__ out)
{
    const int b = blockIdx.x;
    const int h = threadIdx.x;
    float s = 0.f;
    for (int nn = 0; nn < NN; ++nn)
        s += Hvp[((size_t)b * NN + nn) * HH + h];
    __shared__ float pool[HH];
    pool[h] = s * (1.0f / NN);
    __syncthreads();
    if (h < 4) {
        float acc = bfc[h];
        #pragma unroll 8
        for (int k = 0; k < HH; ++k)
            acc = fmaf(pool[k], Wfc[k * 4 + h], acc);
        out[b * 4 + h] = acc;
    }
}

extern "C" void kernel_launch(void* const* d_in, const int* in_sizes, int n_in,
                              void* d_out, int out_size, void* d_ws, size_t ws_size,
                              hipStream_t stream) {
    const float* H_v   = (const float*)d_in[0];
    const float* H_e   = (const float*)d_in[1];
    const float* adj_v = (const float*)d_in[2];
    // d_in[3] = adj_e : dead for the returned output
    const float* T     = (const float*)d_in[4];
    const float* W_v   = (const float*)d_in[5];
    const float* p_v   = (const float*)d_in[6];
    const float* b_v   = (const float*)d_in[7];
    // d_in[8,9,10] = W_e, p_e, b_e : dead
    const float* W_fc  = (const float*)d_in[11];
    const float* b_fc  = (const float*)d_in[12];
    float* out = (float*)d_out;

    float* part = (float*)d_ws;                                   // [8][32][116][128] f32
    float* HvW  = part + (size_t)SPLITS * BATCH * NN * PROW;      // [32][116][64]
    float* Hvp  = HvW  + (size_t)BATCH * NN * HH;                 // [32][116][64]

    mult1_mfma_kernel<<<dim3(SPLITS, BATCH), 256, 0, stream>>>(T, H_e, p_v, part);
    hvw_kernel       <<<dim3((BATCH * NN + 3) / 4), 256, 0, stream>>>(H_v, W_v, HvW);
    node_out_kernel  <<<dim3((BATCH * NN + 3) / 4), 256, 0, stream>>>(part, adj_v, HvW, b_v, Hvp);
    head_kernel      <<<BATCH, 64, 0, stream>>>(Hvp, W_fc, b_fc, out);
}

// Round 4
// 48.694 us; speedup vs baseline: 5.2290x; 1.1076x over previous
//
#include <hip/hip_runtime.h>

#define BATCH 32
#define NN 116
#define EE 1346
#define HH 64
#define SPLITS 8
#define ECH 170        // K per split: 8*170 = 1360 >= 1346
#define PROW 128       // partial-buffer row stride
#define MBLK (SPLITS * BATCH)          // 256 mult1 blocks
#define HROWS 4
#define HBLK ((BATCH * NN) / HROWS)    // 232 hvw blocks

typedef __attribute__((ext_vector_type(8))) short bf16x8;
typedef __attribute__((ext_vector_type(4))) float f32x4;

__device__ __forceinline__ unsigned int pack_bf16(float a, float b) {
    union { float f; unsigned int u; } ua, ub;
    ua.f = a; ub.f = b;
    unsigned int lo = (ua.u + 0x7FFFu + ((ua.u >> 16) & 1u)) >> 16;
    unsigned int hi = (ub.u + 0x7FFFu + ((ub.u >> 16) & 1u)) >> 16;
    return lo | (hi << 16);
}

// ================= K1: mult1 partials (MFMA) + HvW GEMV + out init =================
__global__ __launch_bounds__(256) void stage1_kernel(
    const float* __restrict__ T, const float* __restrict__ He,
    const float* __restrict__ pv,
    const float* __restrict__ Hv, const float* __restrict__ Wv,
    const float* __restrict__ bfc,
    float* __restrict__ part, float* __restrict__ HvW, float* __restrict__ out)
{
    const int blk = blockIdx.x;
    const int tid = threadIdx.x;

    __shared__ float del[192];
    __shared__ unsigned int Tt[128 * 16];    // [row][32k] bf16, XOR-swizzled
    __shared__ unsigned int dTt[128 * 16];

    if (blk < MBLK) {
        // ---- mult1 path: part[s][b][n][m] = sum_{e in split s} T[n,e]*de[e]*T[m,e]
        const int s = blk & 7, b = blk >> 3;
        const int e0 = s * ECH;
        const int cnt = min(ECH, EE - e0);
        const int nsteps = (cnt + 31) >> 5;

        {
            const float p0 = pv[0], p1 = pv[1], p2 = pv[2], p3 = pv[3], p4 = pv[4];
            for (int i = tid; i < 192; i += 256) {
                float v = 0.f;
                if (i < cnt) {
                    const float* he = He + (size_t)(b * EE + e0 + i) * 5;
                    v = he[0]*p0 + he[1]*p1 + he[2]*p2 + he[3]*p3 + he[4]*p4;
                }
                del[i] = v;
            }
        }

        const int n  = tid >> 1;
        const int hf = tid & 1;
        const float* src = T + ((size_t)b * NN + n) * EE + e0;

        float2 pf[8];
        auto prefetch = [&](int c) {
            const int kb = c * 32 + hf * 16;
            #pragma unroll
            for (int q = 0; q < 8; ++q) {
                float2 v = {0.f, 0.f};
                const int k = kb + q * 2;
                if (n < NN) {
                    if (k + 1 < cnt) v = *(const float2*)&src[k];
                    else if (k < cnt) v.x = src[k];
                }
                pf[q] = v;
            }
        };

        const int w = tid >> 6, lane = tid & 63;
        const int RO = (w >> 1) * 64, CO = (w & 1) * 64;
        const int rl = lane & 15, g = lane >> 4;

        f32x4 acc[4][4] = {};

        prefetch(0);
        __syncthreads();

        for (int c = 0; c < nsteps; ++c) {
            {
                const int kb = c * 32 + hf * 16;
                #pragma unroll
                for (int q2 = 0; q2 < 2; ++q2) {
                    uint4 tq, dq;
                    unsigned int* tp = &tq.x;
                    unsigned int* dp = &dq.x;
                    #pragma unroll
                    for (int j = 0; j < 4; ++j) {
                        const float2 v = pf[q2 * 4 + j];
                        const float2 d = *(const float2*)&del[kb + q2 * 8 + 2 * j];
                        tp[j] = pack_bf16(v.x, v.y);
                        dp[j] = pack_bf16(v.x * d.x, v.y * d.y);
                    }
                    const int byteoff = ((n * 64) + (hf * 32) + (q2 * 16)) ^ ((n & 7) << 4);
                    *(uint4*)((char*)Tt  + byteoff) = tq;
                    *(uint4*)((char*)dTt + byteoff) = dq;
                }
            }
            __syncthreads();

            if (c + 1 < nsteps) prefetch(c + 1);

            bf16x8 af[4], bf[4];
            #pragma unroll
            for (int t = 0; t < 4; ++t) {
                const int ra = RO + t * 16 + rl;
                const int rb = CO + t * 16 + rl;
                af[t] = *(const bf16x8*)((const char*)dTt + (((ra * 64) + g * 16) ^ ((ra & 7) << 4)));
                bf[t] = *(const bf16x8*)((const char*)Tt  + (((rb * 64) + g * 16) ^ ((rb & 7) << 4)));
            }
            #pragma unroll
            for (int tn = 0; tn < 4; ++tn)
                #pragma unroll
                for (int tm = 0; tm < 4; ++tm)
                    acc[tn][tm] = __builtin_amdgcn_mfma_f32_16x16x32_bf16(
                        af[tn], bf[tm], acc[tn][tm], 0, 0, 0);
            __syncthreads();
        }

        float* pb = part + ((size_t)(s * BATCH + b) * NN) * PROW;
        #pragma unroll
        for (int tn = 0; tn < 4; ++tn) {
            #pragma unroll
            for (int r = 0; r < 4; ++r) {
                const int grow = RO + tn * 16 + g * 4 + r;
                if (grow >= NN) continue;
                float* rowp = pb + (size_t)grow * PROW + CO;
                #pragma unroll
                for (int tm = 0; tm < 4; ++tm)
                    rowp[tm * 16 + rl] = acc[tn][tm][r];
            }
        }
    } else if (blk < MBLK + HBLK) {
        // ---- HvW path: HvW[b,n,h] = sum_k Hv[b,n,k] * W_v[k,h]
        const int lin = (blk - MBLK) * HROWS + (tid >> 6);
        const int h   = tid & 63;
        const float* hv = Hv + (size_t)lin * NN;
        float acc = 0.f;
        #pragma unroll 4
        for (int k = 0; k < NN; ++k)
            acc = fmaf(hv[k], Wv[k * HH + h], acc);
        HvW[(size_t)lin * HH + h] = acc;
    } else {
        // ---- out init: out[b,o] = b_fc[o]
        if (tid < BATCH * 4) out[tid] = bfc[tid & 3];
    }
}

// ====== K2: Hv' = LReLU((Av .* fix_diag(sum_s part)) @ HvW + b_v); fused head ======
__global__ __launch_bounds__(256) void stage2_kernel(
    const float* __restrict__ part, const float* __restrict__ Av,
    const float* __restrict__ HvW, const float* __restrict__ bv,
    const float* __restrict__ Wfc, float* __restrict__ out)
{
    const int blk = blockIdx.x;              // 232 blocks x 4 rows (116/4=29: no b straddle)
    const int tid = threadIdx.x;
    const int lin0 = blk * 4;
    const int b  = lin0 / NN;
    const int n0 = lin0 - b * NN;

    __shared__ float adjs[4][128];
    __shared__ float xs[4][64];

    const size_t sstr = (size_t)BATCH * NN * PROW;
    #pragma unroll
    for (int it = 0; it < 2; ++it) {
        const int idx = tid + it * 256;
        const int r = idx >> 7, m = idx & 127;
        float v = 0.f;
        if (m < NN) {
            const size_t rowoff = ((size_t)b * NN + n0 + r) * PROW + m;
            float msum = 0.f;
            #pragma unroll
            for (int s = 0; s < SPLITS; ++s) msum += part[s * sstr + rowoff];
            const float a = Av[(size_t)(lin0 + r) * NN + m];
            v = a * ((m == n0 + r) ? 1.0f : msum);
        }
        adjs[r][m] = v;
    }
    __syncthreads();

    const int w = tid >> 6, h = tid & 63;
    const float* hw = HvW + (size_t)b * NN * HH + h;
    float acc = 0.f;
    #pragma unroll 4
    for (int m = 0; m < NN; ++m)
        acc = fmaf(adjs[w][m], hw[(size_t)m * HH], acc);
    float x = acc + bv[h];
    xs[w][h] = (x >= 0.f) ? x : 0.01f * x;   // LeakyReLU(0.01)
    __syncthreads();

    // head contribution: out[b,o] += (1/N) * sum_{r,h} xs[r][h] * Wfc[h,o]
    if (tid < 16) {
        const int r = tid >> 2, o = tid & 3;
        float a = 0.f;
        #pragma unroll 16
        for (int k = 0; k < HH; ++k)
            a = fmaf(xs[r][k], Wfc[k * 4 + o], a);
        atomicAdd(&out[b * 4 + o], a * (1.0f / NN));
    }
}

extern "C" void kernel_launch(void* const* d_in, const int* in_sizes, int n_in,
                              void* d_out, int out_size, void* d_ws, size_t ws_size,
                              hipStream_t stream) {
    const float* H_v   = (const float*)d_in[0];
    const float* H_e   = (const float*)d_in[1];
    const float* adj_v = (const float*)d_in[2];
    // d_in[3] = adj_e : dead for the returned output
    const float* T     = (const float*)d_in[4];
    const float* W_v   = (const float*)d_in[5];
    const float* p_v   = (const float*)d_in[6];
    const float* b_v   = (const float*)d_in[7];
    // d_in[8,9,10] = W_e, p_e, b_e : dead
    const float* W_fc  = (const float*)d_in[11];
    const float* b_fc  = (const float*)d_in[12];
    float* out = (float*)d_out;

    float* part = (float*)d_ws;                                   // [8][32][116][128] f32
    float* HvW  = part + (size_t)SPLITS * BATCH * NN * PROW;      // [32][116][64]

    stage1_kernel<<<MBLK + HBLK + 1, 256, 0, stream>>>(
        T, H_e, p_v, H_v, W_v, b_fc, part, HvW, out);
    stage2_kernel<<<HBLK, 256, 0, stream>>>(
        part, adj_v, HvW, b_v, W_fc, out);
}